// Round 1
// baseline (5568.249 us; speedup 1.0000x reference)
//
#include <hip/hip_runtime.h>

#define B_   8
#define S_   1024
#define D_   1024
#define H_   16
#define DK_  64
#define CF_  256
#define MROWS (B_*S_)          // 8192
#define SCALE_ 512.0f
#define EPS_ 1e-5f

// ---------------- block-wide reduce (256 threads, 4 waves): sum of two values
__device__ __forceinline__ float2 block_reduce_2(float s1, float s2, float* red) {
    #pragma unroll
    for (int off = 32; off; off >>= 1) {
        s1 += __shfl_xor(s1, off);
        s2 += __shfl_xor(s2, off);
    }
    int wid = threadIdx.x >> 6, lane = threadIdx.x & 63;
    if (lane == 0) { red[wid] = s1; red[8 + wid] = s2; }
    __syncthreads();
    if (threadIdx.x == 0) {
        float a = 0.f, b = 0.f;
        int nw = blockDim.x >> 6;
        for (int i = 0; i < nw; i++) { a += red[i]; b += red[8 + i]; }
        red[16] = a; red[17] = b;
    }
    __syncthreads();
    float2 r = make_float2(red[16], red[17]);
    __syncthreads();
    return r;
}

// ---------------- K1: c-path projections + LN  → cvec (3, B, D)
__global__ __launch_bounds__(256) void cproj_ln_kernel(
    const float* __restrict__ c,
    const float* __restrict__ W0, const float* __restrict__ b0,
    const float* __restrict__ g0, const float* __restrict__ be0,
    const float* __restrict__ W1, const float* __restrict__ b1,
    const float* __restrict__ g1, const float* __restrict__ be1,
    const float* __restrict__ W2, const float* __restrict__ b2,
    const float* __restrict__ g2, const float* __restrict__ be2,
    float* __restrict__ cvec)
{
    int b = blockIdx.x, which = blockIdx.y, t = threadIdx.x;
    const float *W, *bias, *g, *be;
    if (which == 0)      { W = W0; bias = b0; g = g0; be = be0; }
    else if (which == 1) { W = W1; bias = b1; g = g1; be = be1; }
    else                 { W = W2; bias = b2; g = g2; be = be2; }

    __shared__ float cs[CF_];
    __shared__ float red[18];
    cs[t] = c[b * CF_ + t];
    __syncthreads();

    float acc[4] = {0.f, 0.f, 0.f, 0.f};
    for (int k = 0; k < CF_; k++) {
        float cv = cs[k];
        const float* wr = W + (size_t)k * D_ + t;
        acc[0] = fmaf(cv, wr[0],   acc[0]);
        acc[1] = fmaf(cv, wr[256], acc[1]);
        acc[2] = fmaf(cv, wr[512], acc[2]);
        acc[3] = fmaf(cv, wr[768], acc[3]);
    }
    float x[4], s1 = 0.f, s2 = 0.f;
    #pragma unroll
    for (int i = 0; i < 4; i++) {
        x[i] = acc[i] + bias[t + 256 * i];
        s1 += x[i];
        s2 = fmaf(x[i], x[i], s2);
    }
    float2 ss = block_reduce_2(s1, s2, red);
    float mu  = ss.x * (1.0f / D_);
    float var = ss.y * (1.0f / D_) - mu * mu;
    float ve  = var + EPS_;
    float rs  = rsqrtf(ve);
    rs = rs * (1.5f - 0.5f * ve * rs * rs);   // Newton step
    #pragma unroll
    for (int i = 0; i < 4; i++) {
        int d = t + 256 * i;
        cvec[((size_t)which * B_ + b) * D_ + d] = (x[i] - mu) * rs * g[d] + be[d];
    }
}

// ---------------- K2/K5: tiled fp32 GEMM  C(M,1024) = A(M,1024) @ W(1024,1024) + bias
#define BM 128
#define BN 128
#define BK 16

__global__ __launch_bounds__(256) void gemm_bias_kernel(
    const float* __restrict__ A,
    const float* __restrict__ W,
    const float* __restrict__ bias,
    float* __restrict__ Cout)
{
    const int K = 1024, N = 1024;
    __shared__ float As[BK][BM];   // transposed A tile
    __shared__ float Bs[BK][BN];

    int t  = threadIdx.x;
    int m0 = blockIdx.y * BM, n0 = blockIdx.x * BN;
    int ty = t >> 4, tx = t & 15;

    float acc[8][8];
    #pragma unroll
    for (int i = 0; i < 8; i++)
        #pragma unroll
        for (int j = 0; j < 8; j++) acc[i][j] = 0.f;

    const float* Ab = A + (size_t)m0 * K;
    const float* Wb = W + n0;

    for (int k0 = 0; k0 < K; k0 += BK) {
        #pragma unroll
        for (int ii = 0; ii < 2; ii++) {           // A tile: 512 float4
            int idx = ii * 256 + t;
            int row = idx >> 2, c4 = idx & 3;
            float4 ga = *(const float4*)(Ab + (size_t)row * K + k0 + c4 * 4);
            As[c4 * 4 + 0][row] = ga.x;
            As[c4 * 4 + 1][row] = ga.y;
            As[c4 * 4 + 2][row] = ga.z;
            As[c4 * 4 + 3][row] = ga.w;
        }
        #pragma unroll
        for (int ii = 0; ii < 2; ii++) {           // B tile: 512 float4
            int idx = ii * 256 + t;
            int row = idx >> 5, c4 = idx & 31;
            *(float4*)(&Bs[row][c4 * 4]) = *(const float4*)(Wb + (size_t)(k0 + row) * N + c4 * 4);
        }
        __syncthreads();
        for (int k = 0; k < BK; k++) {
            float a[8], bb[8];
            *(float4*)(a)      = *(float4*)(&As[k][ty * 8]);
            *(float4*)(a + 4)  = *(float4*)(&As[k][ty * 8 + 4]);
            *(float4*)(bb)     = *(float4*)(&Bs[k][tx * 8]);
            *(float4*)(bb + 4) = *(float4*)(&Bs[k][tx * 8 + 4]);
            #pragma unroll
            for (int i = 0; i < 8; i++)
                #pragma unroll
                for (int j = 0; j < 8; j++)
                    acc[i][j] = fmaf(a[i], bb[j], acc[i][j]);
        }
        __syncthreads();
    }

    #pragma unroll
    for (int i = 0; i < 8; i++) {
        size_t m = m0 + ty * 8 + i;
        float* crow = Cout + m * N + n0 + tx * 8;
        const float* bp = bias + n0 + tx * 8;
        float4 o0 = { acc[i][0] + bp[0], acc[i][1] + bp[1], acc[i][2] + bp[2], acc[i][3] + bp[3] };
        float4 o1 = { acc[i][4] + bp[4], acc[i][5] + bp[5], acc[i][6] + bp[6], acc[i][7] + bp[7] };
        *(float4*)(crow)     = o0;
        *(float4*)(crow + 4) = o1;
    }
}

// ---------------- K3: per-row LayerNorm + add c-vector (in place on qkv buffers)
__global__ __launch_bounds__(256) void ln_add_kernel(
    float* __restrict__ qb,                     // (3, MROWS, D) in place
    const float* __restrict__ g0, const float* __restrict__ be0,
    const float* __restrict__ g1, const float* __restrict__ be1,
    const float* __restrict__ g2, const float* __restrict__ be2,
    const float* __restrict__ cvec)             // (3, B, D)
{
    int row = blockIdx.x, which = blockIdx.y, t = threadIdx.x;
    const float *g, *be;
    if (which == 0)      { g = g0; be = be0; }
    else if (which == 1) { g = g1; be = be1; }
    else                 { g = g2; be = be2; }

    __shared__ float red[18];
    float* p = qb + ((size_t)which * MROWS + row) * D_;
    const float* cv = cvec + ((size_t)which * B_ + (row / S_)) * D_;

    float4 x = *(const float4*)(p + t * 4);
    float s1 = x.x + x.y + x.z + x.w;
    float s2 = x.x * x.x + x.y * x.y + x.z * x.z + x.w * x.w;
    float2 ss = block_reduce_2(s1, s2, red);
    float mu  = ss.x * (1.0f / D_);
    float var = ss.y * (1.0f / D_) - mu * mu;
    float ve  = var + EPS_;
    float rs  = rsqrtf(ve);
    rs = rs * (1.5f - 0.5f * ve * rs * rs);

    float4 gv  = *(const float4*)(g  + t * 4);
    float4 bev = *(const float4*)(be + t * 4);
    float4 cvv = *(const float4*)(cv + t * 4);
    float4 o;
    o.x = (x.x - mu) * rs * gv.x + bev.x + cvv.x;
    o.y = (x.y - mu) * rs * gv.y + bev.y + cvv.y;
    o.z = (x.z - mu) * rs * gv.z + bev.z + cvv.z;
    o.w = (x.w - mu) * rs * gv.w + bev.w + cvv.w;
    *(float4*)(p + t * 4) = o;
}

// ---------------- K4: attention per (qtile32, h, b): scores+softmax+attn write+ctx
__global__ __launch_bounds__(1024) void attn_kernel(
    const float* __restrict__ qb,   // q | k | v, each (B,S,D)
    float* __restrict__ attn_out,   // (B,H,S,S)
    float* __restrict__ ctx)        // (B,S,D)
{
    __shared__ float Sc[32][1024];  // 128 KB
    __shared__ float Qs[32][DK_];   // 8 KB
    __shared__ float RL[32];

    const float* q = qb;
    const float* kmat = qb + (size_t)MROWS * D_;
    const float* v = qb + 2 * (size_t)MROWS * D_;

    int qt = blockIdx.x, h = blockIdx.y, b = blockIdx.z;
    int t = threadIdx.x;
    int qr0 = qt * 32;
    size_t base_bh = ((size_t)b * S_) * D_ + (size_t)h * DK_;

    // A: load scaled Q tile
    #pragma unroll
    for (int i = 0; i < 2; i++) {
        int e = t + i * 1024;
        int r = e >> 6, j = e & 63;
        Qs[r][j] = q[base_bh + (size_t)(qr0 + r) * D_ + j] * SCALE_;
    }
    __syncthreads();

    // B: scores — thread t owns key-column t
    {
        int col = t;
        const float* kp = kmat + base_bh + (size_t)col * D_;
        float4 kv[16];
        #pragma unroll
        for (int jj = 0; jj < 16; jj++) kv[jj] = *(const float4*)(kp + jj * 4);
        for (int r = 0; r < 32; r++) {
            const float4* qr4 = (const float4*)(&Qs[r][0]);
            float sx = 0.f, sy = 0.f, sz = 0.f, sw = 0.f;
            #pragma unroll
            for (int jj = 0; jj < 16; jj++) {
                float4 qv = qr4[jj];
                sx = fmaf(qv.x, kv[jj].x, sx);
                sy = fmaf(qv.y, kv[jj].y, sy);
                sz = fmaf(qv.z, kv[jj].z, sz);
                sw = fmaf(qv.w, kv[jj].w, sw);
            }
            Sc[r][col] = (sx + sy) + (sz + sw);
        }
    }
    __syncthreads();

    // C: row max, exp, sum — wave w handles rows 2w, 2w+1
    {
        int w = t >> 6, lane = t & 63;
        #pragma unroll
        for (int rr = 0; rr < 2; rr++) {
            int r = w * 2 + rr;
            float vals[16];
            float m = -3.4e38f;
            #pragma unroll
            for (int i = 0; i < 16; i++) { vals[i] = Sc[r][lane + 64 * i]; m = fmaxf(m, vals[i]); }
            #pragma unroll
            for (int off = 32; off; off >>= 1) m = fmaxf(m, __shfl_xor(m, off));
            float sum = 0.f;
            #pragma unroll
            for (int i = 0; i < 16; i++) {
                float e = __expf(vals[i] - m);
                Sc[r][lane + 64 * i] = e;
                sum += e;
            }
            #pragma unroll
            for (int off = 32; off; off >>= 1) sum += __shfl_xor(sum, off);
            if (lane == 0) RL[r] = 1.0f / sum;
        }
    }
    __syncthreads();

    // D1: write normalized attn (coalesced float4)
    {
        float* abase = attn_out + (((size_t)b * H_ + h) * S_ + qr0) * S_;
        int rg = t >> 8;
        int c4 = (t & 255) * 4;
        #pragma unroll
        for (int rr = 0; rr < 8; rr++) {
            int r = rr * 4 + rg;
            float rl = RL[r];
            float4 e4 = *(float4*)(&Sc[r][c4]);
            float4 o4 = { e4.x * rl, e4.y * rl, e4.z * rl, e4.w * rl };
            *(float4*)(abase + (size_t)r * S_ + c4) = o4;
        }
    }

    // D2: ctx partials — thread (d = t&63, g = t>>6) covers cols g*64..g*64+63, all 32 rows
    float acc[32];
    {
        int d = t & 63, g6 = t >> 6;
        const float* vp = v + base_bh + (size_t)(g6 * 64) * D_ + d;
        float vv[64];
        #pragma unroll
        for (int cc = 0; cc < 64; cc++) vv[cc] = vp[(size_t)cc * D_];
        for (int r = 0; r < 32; r++) {
            const float4* pr = (const float4*)(&Sc[r][g6 * 64]);
            float a0 = 0.f, a1 = 0.f, a2 = 0.f, a3 = 0.f;
            #pragma unroll
            for (int c4 = 0; c4 < 16; c4++) {
                float4 p4 = pr[c4];
                a0 = fmaf(p4.x, vv[c4 * 4 + 0], a0);
                a1 = fmaf(p4.y, vv[c4 * 4 + 1], a1);
                a2 = fmaf(p4.z, vv[c4 * 4 + 2], a2);
                a3 = fmaf(p4.w, vv[c4 * 4 + 3], a3);
            }
            acc[r] = (a0 + a1) + (a2 + a3);
        }
    }
    __syncthreads();

    // E: spill partials to LDS (reuse Sc region: part[g][r][d])
    {
        float* scf = &Sc[0][0];
        int d = t & 63, g6 = t >> 6;
        #pragma unroll
        for (int r = 0; r < 32; r++) scf[g6 * 2048 + r * 64 + d] = acc[r];
    }
    __syncthreads();

    // F: reduce 16 partials, scale by 1/l, write ctx
    {
        float* scf = &Sc[0][0];
        #pragma unroll
        for (int i = 0; i < 2; i++) {
            int o = t + i * 1024;
            int r = o >> 6, d = o & 63;
            float ssum = 0.f;
            #pragma unroll
            for (int g6 = 0; g6 < 16; g6++) ssum += scf[g6 * 2048 + o];
            ctx[base_bh + (size_t)(qr0 + r) * D_ + d] = ssum * RL[r];
        }
    }
}

// ---------------- launch
extern "C" void kernel_launch(void* const* d_in, const int* in_sizes, int n_in,
                              void* d_out, int out_size, void* d_ws, size_t ws_size,
                              hipStream_t stream) {
    const float* Q    = (const float*)d_in[0];
    const float* c    = (const float*)d_in[1];
    const float* Wq   = (const float*)d_in[2];
    const float* bq   = (const float*)d_in[3];
    const float* Wk   = (const float*)d_in[4];
    const float* bk   = (const float*)d_in[5];
    const float* Wv   = (const float*)d_in[6];
    const float* bv   = (const float*)d_in[7];
    const float* Wcq  = (const float*)d_in[8];
    const float* bcq  = (const float*)d_in[9];
    const float* Wck  = (const float*)d_in[10];
    const float* bck  = (const float*)d_in[11];
    const float* Wcv  = (const float*)d_in[12];
    const float* bcv  = (const float*)d_in[13];
    const float* g_q  = (const float*)d_in[14];
    const float* be_q = (const float*)d_in[15];
    const float* g_qc = (const float*)d_in[16];
    const float* be_qc= (const float*)d_in[17];
    const float* g_k  = (const float*)d_in[18];
    const float* be_k = (const float*)d_in[19];
    const float* g_kc = (const float*)d_in[20];
    const float* be_kc= (const float*)d_in[21];
    const float* g_v  = (const float*)d_in[22];
    const float* be_v = (const float*)d_in[23];
    const float* g_vc = (const float*)d_in[24];
    const float* be_vc= (const float*)d_in[25];
    const float* Wo   = (const float*)d_in[26];
    const float* bo   = (const float*)d_in[27];

    const size_t MD = (size_t)MROWS * D_;
    float* ws   = (float*)d_ws;
    float* qb   = ws;                 // 3 * MD  (q | k | v)
    float* ctx  = ws + 3 * MD;        // MD
    float* cvec = ws + 4 * MD;        // 3 * B * D

    float* out_p  = (float*)d_out;                       // (B,S,D)
    float* attn_p = (float*)d_out + (size_t)MROWS * D_;  // (B,H,S,S)

    // K1: c-path (tiny)
    cproj_ln_kernel<<<dim3(B_, 3), 256, 0, stream>>>(
        c, Wcq, bcq, g_qc, be_qc, Wck, bck, g_kc, be_kc, Wcv, bcv, g_vc, be_vc, cvec);

    // K2: three projection GEMMs (+bias)
    gemm_bias_kernel<<<dim3(1024 / BN, MROWS / BM), 256, 0, stream>>>(Q, Wq, bq, qb);
    gemm_bias_kernel<<<dim3(1024 / BN, MROWS / BM), 256, 0, stream>>>(Q, Wk, bk, qb + MD);
    gemm_bias_kernel<<<dim3(1024 / BN, MROWS / BM), 256, 0, stream>>>(Q, Wv, bv, qb + 2 * MD);

    // K3: LN + add broadcast c-vector (in place)
    ln_add_kernel<<<dim3(MROWS, 3), 256, 0, stream>>>(
        qb, g_q, be_q, g_k, be_k, g_v, be_v, cvec);

    // K4: attention
    attn_kernel<<<dim3(S_ / 32, H_, B_), 1024, 0, stream>>>(qb, attn_p, ctx);

    // K5: output projection
    gemm_bias_kernel<<<dim3(1024 / BN, MROWS / BM), 256, 0, stream>>>(ctx, Wo, bo, out_p);
}

// Round 2
// 2990.848 us; speedup vs baseline: 1.8618x; 1.8618x over previous
//
#include <hip/hip_runtime.h>

#define B_   8
#define S_   1024
#define D_   1024
#define H_   16
#define DK_  64
#define CF_  256
#define MROWS (B_*S_)          // 8192
#define SCALE_ 512.0f
#define EPS_ 1e-5f

// ---------------- wave-wide reduces (64 lanes)
__device__ __forceinline__ float wave_max64(float v) {
    #pragma unroll
    for (int off = 32; off; off >>= 1) v = fmaxf(v, __shfl_xor(v, off));
    return v;
}
__device__ __forceinline__ float wave_sum64(float v) {
    #pragma unroll
    for (int off = 32; off; off >>= 1) v += __shfl_xor(v, off);
    return v;
}

// ---------------- block-wide reduce (256 threads, 4 waves): sum of two values
__device__ __forceinline__ float2 block_reduce_2(float s1, float s2, float* red) {
    #pragma unroll
    for (int off = 32; off; off >>= 1) {
        s1 += __shfl_xor(s1, off);
        s2 += __shfl_xor(s2, off);
    }
    int wid = threadIdx.x >> 6, lane = threadIdx.x & 63;
    if (lane == 0) { red[wid] = s1; red[8 + wid] = s2; }
    __syncthreads();
    if (threadIdx.x == 0) {
        float a = 0.f, b = 0.f;
        int nw = blockDim.x >> 6;
        for (int i = 0; i < nw; i++) { a += red[i]; b += red[8 + i]; }
        red[16] = a; red[17] = b;
    }
    __syncthreads();
    float2 r = make_float2(red[16], red[17]);
    __syncthreads();
    return r;
}

// ---------------- K1: c-path projections + LN  → cvec (3, B, D)
__global__ __launch_bounds__(256) void cproj_ln_kernel(
    const float* __restrict__ c,
    const float* __restrict__ W0, const float* __restrict__ b0,
    const float* __restrict__ g0, const float* __restrict__ be0,
    const float* __restrict__ W1, const float* __restrict__ b1,
    const float* __restrict__ g1, const float* __restrict__ be1,
    const float* __restrict__ W2, const float* __restrict__ b2,
    const float* __restrict__ g2, const float* __restrict__ be2,
    float* __restrict__ cvec)
{
    int b = blockIdx.x, which = blockIdx.y, t = threadIdx.x;
    const float *W, *bias, *g, *be;
    if (which == 0)      { W = W0; bias = b0; g = g0; be = be0; }
    else if (which == 1) { W = W1; bias = b1; g = g1; be = be1; }
    else                 { W = W2; bias = b2; g = g2; be = be2; }

    __shared__ float cs[CF_];
    __shared__ float red[18];
    cs[t] = c[b * CF_ + t];
    __syncthreads();

    float acc[4] = {0.f, 0.f, 0.f, 0.f};
    for (int k = 0; k < CF_; k++) {
        float cv = cs[k];
        const float* wr = W + (size_t)k * D_ + t;
        acc[0] = fmaf(cv, wr[0],   acc[0]);
        acc[1] = fmaf(cv, wr[256], acc[1]);
        acc[2] = fmaf(cv, wr[512], acc[2]);
        acc[3] = fmaf(cv, wr[768], acc[3]);
    }
    float x[4], s1 = 0.f, s2 = 0.f;
    #pragma unroll
    for (int i = 0; i < 4; i++) {
        x[i] = acc[i] + bias[t + 256 * i];
        s1 += x[i];
        s2 = fmaf(x[i], x[i], s2);
    }
    float2 ss = block_reduce_2(s1, s2, red);
    float mu  = ss.x * (1.0f / D_);
    float var = ss.y * (1.0f / D_) - mu * mu;
    float ve  = var + EPS_;
    float rs  = rsqrtf(ve);
    rs = rs * (1.5f - 0.5f * ve * rs * rs);   // Newton step
    #pragma unroll
    for (int i = 0; i < 4; i++) {
        int d = t + 256 * i;
        cvec[((size_t)which * B_ + b) * D_ + d] = (x[i] - mu) * rs * g[d] + be[d];
    }
}

// ---------------- K2/K5: tiled fp32 GEMM  C(M,1024) = A(M,1024) @ W(1024,1024) + bias
#define BM 128
#define BN 128
#define BK 16

__global__ __launch_bounds__(256) void gemm_bias_kernel(
    const float* __restrict__ A,
    const float* __restrict__ W,
    const float* __restrict__ bias,
    float* __restrict__ Cout)
{
    const int K = 1024, N = 1024;
    __shared__ float As[BK][BM];   // transposed A tile
    __shared__ float Bs[BK][BN];

    int t  = threadIdx.x;
    int m0 = blockIdx.y * BM, n0 = blockIdx.x * BN;
    int ty = t >> 4, tx = t & 15;

    float acc[8][8];
    #pragma unroll
    for (int i = 0; i < 8; i++)
        #pragma unroll
        for (int j = 0; j < 8; j++) acc[i][j] = 0.f;

    const float* Ab = A + (size_t)m0 * K;
    const float* Wb = W + n0;

    for (int k0 = 0; k0 < K; k0 += BK) {
        #pragma unroll
        for (int ii = 0; ii < 2; ii++) {           // A tile: 512 float4
            int idx = ii * 256 + t;
            int row = idx >> 2, c4 = idx & 3;
            float4 ga = *(const float4*)(Ab + (size_t)row * K + k0 + c4 * 4);
            As[c4 * 4 + 0][row] = ga.x;
            As[c4 * 4 + 1][row] = ga.y;
            As[c4 * 4 + 2][row] = ga.z;
            As[c4 * 4 + 3][row] = ga.w;
        }
        #pragma unroll
        for (int ii = 0; ii < 2; ii++) {           // B tile: 512 float4
            int idx = ii * 256 + t;
            int row = idx >> 5, c4 = idx & 31;
            *(float4*)(&Bs[row][c4 * 4]) = *(const float4*)(Wb + (size_t)(k0 + row) * N + c4 * 4);
        }
        __syncthreads();
        for (int k = 0; k < BK; k++) {
            float a[8], bb[8];
            *(float4*)(a)      = *(float4*)(&As[k][ty * 8]);
            *(float4*)(a + 4)  = *(float4*)(&As[k][ty * 8 + 4]);
            *(float4*)(bb)     = *(float4*)(&Bs[k][tx * 8]);
            *(float4*)(bb + 4) = *(float4*)(&Bs[k][tx * 8 + 4]);
            #pragma unroll
            for (int i = 0; i < 8; i++)
                #pragma unroll
                for (int j = 0; j < 8; j++)
                    acc[i][j] = fmaf(a[i], bb[j], acc[i][j]);
        }
        __syncthreads();
    }

    #pragma unroll
    for (int i = 0; i < 8; i++) {
        size_t m = m0 + ty * 8 + i;
        float* crow = Cout + m * N + n0 + tx * 8;
        const float* bp = bias + n0 + tx * 8;
        float4 o0 = { acc[i][0] + bp[0], acc[i][1] + bp[1], acc[i][2] + bp[2], acc[i][3] + bp[3] };
        float4 o1 = { acc[i][4] + bp[4], acc[i][5] + bp[5], acc[i][6] + bp[6], acc[i][7] + bp[7] };
        *(float4*)(crow)     = o0;
        *(float4*)(crow + 4) = o1;
    }
}

// ---------------- K3: per-row LayerNorm + add c-vector (in place on qkv buffers)
__global__ __launch_bounds__(256) void ln_add_kernel(
    float* __restrict__ qb,                     // (3, MROWS, D) in place
    const float* __restrict__ g0, const float* __restrict__ be0,
    const float* __restrict__ g1, const float* __restrict__ be1,
    const float* __restrict__ g2, const float* __restrict__ be2,
    const float* __restrict__ cvec)             // (3, B, D)
{
    int row = blockIdx.x, which = blockIdx.y, t = threadIdx.x;
    const float *g, *be;
    if (which == 0)      { g = g0; be = be0; }
    else if (which == 1) { g = g1; be = be1; }
    else                 { g = g2; be = be2; }

    __shared__ float red[18];
    float* p = qb + ((size_t)which * MROWS + row) * D_;
    const float* cv = cvec + ((size_t)which * B_ + (row / S_)) * D_;

    float4 x = *(const float4*)(p + t * 4);
    float s1 = x.x + x.y + x.z + x.w;
    float s2 = x.x * x.x + x.y * x.y + x.z * x.z + x.w * x.w;
    float2 ss = block_reduce_2(s1, s2, red);
    float mu  = ss.x * (1.0f / D_);
    float var = ss.y * (1.0f / D_) - mu * mu;
    float ve  = var + EPS_;
    float rs  = rsqrtf(ve);
    rs = rs * (1.5f - 0.5f * ve * rs * rs);

    float4 gv  = *(const float4*)(g  + t * 4);
    float4 bev = *(const float4*)(be + t * 4);
    float4 cvv = *(const float4*)(cv + t * 4);
    float4 o;
    o.x = (x.x - mu) * rs * gv.x + bev.x + cvv.x;
    o.y = (x.y - mu) * rs * gv.y + bev.y + cvv.y;
    o.z = (x.z - mu) * rs * gv.z + bev.z + cvv.z;
    o.w = (x.w - mu) * rs * gv.w + bev.w + cvv.w;
    *(float4*)(p + t * 4) = o;
}

// ---------------- K4: fused attention, tile-deferred softmax
// grid: 4096 blocks (swizzled), block 512 threads (8 waves)
// wave w owns q-rows 4w..4w+3; lane owns one key column per 64-wide K tile
__global__ __launch_bounds__(512) void attn_kernel(
    const float* __restrict__ qb,   // q | k | v, each (B,S,D)
    float* __restrict__ attn_out,   // (B,H,S,S)
    float* __restrict__ ctx)        // (B,S,D)
{
    __shared__ float Qs[32][68];              // scaled Q tile (pad 68: b128 2-way max)
    __shared__ float Ks[2][64][68];           // K tile double buffer
    __shared__ unsigned short P[32][1024];    // exp(s - Mj) as bf16
    __shared__ float Mj[32][16];              // per-tile max
    __shared__ float Lj[32][16];              // per-tile expsum
    __shared__ float Mfin[32], Linv[32];

    const float* q    = qb;
    const float* kmat = qb + (size_t)MROWS * D_;
    const float* v    = qb + 2 * (size_t)MROWS * D_;

    // XCD swizzle: all 32 q-tiles of one (b,h) land on the same XCD
    int i  = blockIdx.x;
    int sl = i >> 3;
    int g  = (i & 7) + 8 * (sl >> 5);   // g = h + 16*b  (0..127)
    int qt = sl & 31;
    int b  = g >> 4, h = g & 15;

    int t = threadIdx.x;
    int w = t >> 6, lane = t & 63;
    int qr0 = qt * 32;
    size_t base_bh = (size_t)b * S_ * D_ + (size_t)h * DK_;

    // load scaled Q tile: thread -> (row = t>>4, 4 cols)
    {
        int r = t >> 4, j4 = (t & 15) * 4;
        float4 qv = *(const float4*)(q + base_bh + (size_t)(qr0 + r) * D_ + j4);
        Qs[r][j4 + 0] = qv.x * SCALE_;
        Qs[r][j4 + 1] = qv.y * SCALE_;
        Qs[r][j4 + 2] = qv.z * SCALE_;
        Qs[r][j4 + 3] = qv.w * SCALE_;
    }
    // load K tile 0
    #pragma unroll
    for (int i2 = 0; i2 < 2; ++i2) {
        int idx = i2 * 512 + t, row = idx >> 4, j4 = (idx & 15) * 4;
        *(float4*)&Ks[0][row][j4] =
            *(const float4*)(kmat + base_bh + (size_t)row * D_ + j4);
    }
    __syncthreads();

    // ---- score pass over 16 K tiles ----
    #pragma unroll 1
    for (int j = 0; j < 16; ++j) {
        int cur = j & 1;
        float4 pf0, pf1;
        if (j < 15) {   // prefetch next K tile to regs
            int idx0 = t,       row0 = idx0 >> 4, c0 = (idx0 & 15) * 4;
            int idx1 = 512 + t, row1 = idx1 >> 4, c1 = (idx1 & 15) * 4;
            pf0 = *(const float4*)(kmat + base_bh + (size_t)((j + 1) * 64 + row0) * D_ + c0);
            pf1 = *(const float4*)(kmat + base_bh + (size_t)((j + 1) * 64 + row1) * D_ + c1);
        }
        // lane's key column into regs
        float4 kv[16];
        #pragma unroll
        for (int kk = 0; kk < 16; ++kk) kv[kk] = *(const float4*)&Ks[cur][lane][kk * 4];

        #pragma unroll
        for (int rr = 0; rr < 4; ++rr) {
            int r = w * 4 + rr;
            float a0 = 0.f, a1 = 0.f, a2 = 0.f, a3 = 0.f;
            #pragma unroll
            for (int kk = 0; kk < 16; ++kk) {
                float4 q4 = *(const float4*)&Qs[r][kk * 4];   // broadcast read
                a0 = fmaf(q4.x, kv[kk].x, a0);
                a1 = fmaf(q4.y, kv[kk].y, a1);
                a2 = fmaf(q4.z, kv[kk].z, a2);
                a3 = fmaf(q4.w, kv[kk].w, a3);
            }
            float sv = (a0 + a1) + (a2 + a3);
            float m  = wave_max64(sv);
            float p  = __expf(sv - m);
            float l  = wave_sum64(p);
            unsigned u = __float_as_uint(p);        // round-to-nearest-even bf16
            u += 0x7fffu + ((u >> 16) & 1u);
            P[r][j * 64 + lane] = (unsigned short)(u >> 16);
            if (lane == 0) { Mj[r][j] = m; Lj[r][j] = l; }
        }
        if (j < 15) {
            int idx0 = t,       row0 = idx0 >> 4, c0 = (idx0 & 15) * 4;
            int idx1 = 512 + t, row1 = idx1 >> 4, c1 = (idx1 & 15) * 4;
            *(float4*)&Ks[1 - cur][row0][c0] = pf0;
            *(float4*)&Ks[1 - cur][row1][c1] = pf1;
            __syncthreads();
        }
    }
    __syncthreads();

    // ---- finalize per-row max / inverse sum ----
    if (t < 32) {
        float m = -3.4e38f;
        #pragma unroll
        for (int j2 = 0; j2 < 16; ++j2) m = fmaxf(m, Mj[t][j2]);
        float L = 0.f;
        #pragma unroll
        for (int j2 = 0; j2 < 16; ++j2) L += Lj[t][j2] * __expf(Mj[t][j2] - m);
        Mfin[t] = m;
        Linv[t] = 1.0f / L;
    }
    __syncthreads();

    // ---- write normalized attn (coalesced float4) ----
    {
        float* abase = attn_out + (((size_t)b * H_ + h) * S_ + qr0) * S_;
        #pragma unroll
        for (int rr = 0; rr < 4; ++rr) {
            int r = w * 4 + rr;
            float mf = Mfin[r], li = Linv[r];
            #pragma unroll
            for (int chunk = 0; chunk < 4; ++chunk) {
                int cc = chunk * 256 + lane * 4;
                int jidx = cc >> 6;
                float scl = __expf(Mj[r][jidx] - mf) * li;
                uint2 pu = *(const uint2*)&P[r][cc];
                float4 o;
                o.x = __uint_as_float(pu.x << 16) * scl;
                o.y = __uint_as_float(pu.x & 0xffff0000u) * scl;
                o.z = __uint_as_float(pu.y << 16) * scl;
                o.w = __uint_as_float(pu.y & 0xffff0000u) * scl;
                *(float4*)(abase + (size_t)r * S_ + cc) = o;
            }
        }
    }

    // ---- PV: lane owns output dim d = lane; V read from global (L1/L2-served) ----
    float acc[4] = {0.f, 0.f, 0.f, 0.f};
    const float* vb = v + base_bh + lane;
    #pragma unroll 1
    for (int j = 0; j < 16; ++j) {
        float sc4[4];
        #pragma unroll
        for (int rr = 0; rr < 4; ++rr) {
            int r = w * 4 + rr;
            sc4[rr] = __expf(Mj[r][j] - Mfin[r]);
        }
        const float* vj = vb + (size_t)(j * 64) * D_;
        float ta[4] = {0.f, 0.f, 0.f, 0.f};
        float v0 = vj[0], v1 = vj[D_], v2 = vj[2 * D_], v3 = vj[3 * D_];
        #pragma unroll
        for (int ch = 0; ch < 16; ++ch) {
            float n0 = 0.f, n1 = 0.f, n2 = 0.f, n3 = 0.f;
            if (ch < 15) {
                const float* vn = vj + (size_t)(ch * 4 + 4) * D_;
                n0 = vn[0]; n1 = vn[D_]; n2 = vn[2 * D_]; n3 = vn[3 * D_];
            }
            #pragma unroll
            for (int rr = 0; rr < 4; ++rr) {
                int r = w * 4 + rr;
                uint2 pu = *(const uint2*)&P[r][j * 64 + ch * 4];   // broadcast
                ta[rr] = fmaf(__uint_as_float(pu.x << 16),          v0, ta[rr]);
                ta[rr] = fmaf(__uint_as_float(pu.x & 0xffff0000u),  v1, ta[rr]);
                ta[rr] = fmaf(__uint_as_float(pu.y << 16),          v2, ta[rr]);
                ta[rr] = fmaf(__uint_as_float(pu.y & 0xffff0000u),  v3, ta[rr]);
            }
            v0 = n0; v1 = n1; v2 = n2; v3 = n3;
        }
        #pragma unroll
        for (int rr = 0; rr < 4; ++rr) acc[rr] = fmaf(ta[rr], sc4[rr], acc[rr]);
    }
    #pragma unroll
    for (int rr = 0; rr < 4; ++rr) {
        int r = w * 4 + rr;
        ctx[base_bh + (size_t)(qr0 + r) * D_ + lane] = acc[rr] * Linv[r];
    }
}

// ---------------- launch
extern "C" void kernel_launch(void* const* d_in, const int* in_sizes, int n_in,
                              void* d_out, int out_size, void* d_ws, size_t ws_size,
                              hipStream_t stream) {
    const float* Q    = (const float*)d_in[0];
    const float* c    = (const float*)d_in[1];
    const float* Wq   = (const float*)d_in[2];
    const float* bq   = (const float*)d_in[3];
    const float* Wk   = (const float*)d_in[4];
    const float* bk   = (const float*)d_in[5];
    const float* Wv   = (const float*)d_in[6];
    const float* bv   = (const float*)d_in[7];
    const float* Wcq  = (const float*)d_in[8];
    const float* bcq  = (const float*)d_in[9];
    const float* Wck  = (const float*)d_in[10];
    const float* bck  = (const float*)d_in[11];
    const float* Wcv  = (const float*)d_in[12];
    const float* bcv  = (const float*)d_in[13];
    const float* g_q  = (const float*)d_in[14];
    const float* be_q = (const float*)d_in[15];
    const float* g_qc = (const float*)d_in[16];
    const float* be_qc= (const float*)d_in[17];
    const float* g_k  = (const float*)d_in[18];
    const float* be_k = (const float*)d_in[19];
    const float* g_kc = (const float*)d_in[20];
    const float* be_kc= (const float*)d_in[21];
    const float* g_v  = (const float*)d_in[22];
    const float* be_v = (const float*)d_in[23];
    const float* g_vc = (const float*)d_in[24];
    const float* be_vc= (const float*)d_in[25];
    const float* Wo   = (const float*)d_in[26];
    const float* bo   = (const float*)d_in[27];

    const size_t MD = (size_t)MROWS * D_;
    float* ws   = (float*)d_ws;
    float* qb   = ws;                 // 3 * MD  (q | k | v)
    float* ctx  = ws + 3 * MD;        // MD
    float* cvec = ws + 4 * MD;        // 3 * B * D

    float* out_p  = (float*)d_out;                       // (B,S,D)
    float* attn_p = (float*)d_out + (size_t)MROWS * D_;  // (B,H,S,S)

    // K1: c-path (tiny)
    cproj_ln_kernel<<<dim3(B_, 3), 256, 0, stream>>>(
        c, Wcq, bcq, g_qc, be_qc, Wck, bck, g_kc, be_kc, Wcv, bcv, g_vc, be_vc, cvec);

    // K2: three projection GEMMs (+bias)
    gemm_bias_kernel<<<dim3(1024 / BN, MROWS / BM), 256, 0, stream>>>(Q, Wq, bq, qb);
    gemm_bias_kernel<<<dim3(1024 / BN, MROWS / BM), 256, 0, stream>>>(Q, Wk, bk, qb + MD);
    gemm_bias_kernel<<<dim3(1024 / BN, MROWS / BM), 256, 0, stream>>>(Q, Wv, bv, qb + 2 * MD);

    // K3: LN + add broadcast c-vector (in place)
    ln_add_kernel<<<dim3(MROWS, 3), 256, 0, stream>>>(
        qb, g_q, be_q, g_k, be_k, g_v, be_v, cvec);

    // K4: fused attention
    attn_kernel<<<dim3(4096), 512, 0, stream>>>(qb, attn_p, ctx);

    // K5: output projection
    gemm_bias_kernel<<<dim3(1024 / BN, MROWS / BM), 256, 0, stream>>>(ctx, Wo, bo, out_p);
}

// Round 4
// 2487.894 us; speedup vs baseline: 2.2381x; 1.2022x over previous
//
#include <hip/hip_runtime.h>

#define B_   8
#define S_   1024
#define D_   1024
#define H_   16
#define DK_  64
#define CF_  256
#define MROWS (B_*S_)          // 8192
#define SCALE_ 512.0f
#define EPS_ 1e-5f

typedef unsigned short u16;
typedef __attribute__((ext_vector_type(8))) short short8;   // 8 bf16 = 4 VGPR
typedef __attribute__((ext_vector_type(4))) float f32x4;

__device__ __forceinline__ u16 bf16_rn(float x) {
    unsigned u = __float_as_uint(x);
    u += 0x7fffu + ((u >> 16) & 1u);
    return (u16)(u >> 16);
}
__device__ __forceinline__ float bf16_tof(u16 h) {
    return __uint_as_float(((unsigned)h) << 16);
}
__device__ __forceinline__ unsigned pack2(u16 a, u16 b) {
    return (unsigned)a | ((unsigned)b << 16);
}

// ---------------- wave reduces
__device__ __forceinline__ float wave_max64(float v) {
    #pragma unroll
    for (int off = 32; off; off >>= 1) v = fmaxf(v, __shfl_xor(v, off));
    return v;
}
__device__ __forceinline__ float wave_sum64(float v) {
    #pragma unroll
    for (int off = 32; off; off >>= 1) v += __shfl_xor(v, off);
    return v;
}

__device__ __forceinline__ float2 block_reduce_2(float s1, float s2, float* red) {
    #pragma unroll
    for (int off = 32; off; off >>= 1) {
        s1 += __shfl_xor(s1, off);
        s2 += __shfl_xor(s2, off);
    }
    int wid = threadIdx.x >> 6, lane = threadIdx.x & 63;
    if (lane == 0) { red[wid] = s1; red[8 + wid] = s2; }
    __syncthreads();
    if (threadIdx.x == 0) {
        float a = 0.f, b = 0.f;
        int nw = blockDim.x >> 6;
        for (int i = 0; i < nw; i++) { a += red[i]; b += red[8 + i]; }
        red[16] = a; red[17] = b;
    }
    __syncthreads();
    float2 r = make_float2(red[16], red[17]);
    __syncthreads();
    return r;
}

// ---------------- conversion: A-side split (NS = 3 or 1), row-major [M][1024]
template<int NS>
__global__ __launch_bounds__(256) void convA_kernel(
    const float* __restrict__ in, u16* __restrict__ h,
    u16* __restrict__ m, u16* __restrict__ l, int n4)
{
    int i = blockIdx.x * blockDim.x + threadIdx.x;
    int stride = gridDim.x * blockDim.x;
    for (; i < n4; i += stride) {
        float4 x = ((const float4*)in)[i];
        float xs[4] = {x.x, x.y, x.z, x.w};
        u16 hh[4], mm[4], ll[4];
        #pragma unroll
        for (int j = 0; j < 4; ++j) {
            float v = xs[j];
            u16 hv = bf16_rn(v); hh[j] = hv;
            if (NS == 3) {
                float r1 = v - bf16_tof(hv);
                u16 mv = bf16_rn(r1); mm[j] = mv;
                float r2 = r1 - bf16_tof(mv);
                ll[j] = bf16_rn(r2);
            }
        }
        ((uint2*)h)[i] = make_uint2(pack2(hh[0], hh[1]), pack2(hh[2], hh[3]));
        if (NS == 3) {
            ((uint2*)m)[i] = make_uint2(pack2(mm[0], mm[1]), pack2(mm[2], mm[3]));
            ((uint2*)l)[i] = make_uint2(pack2(ll[0], ll[1]), pack2(ll[2], ll[3]));
        }
    }
}

// ---------------- conversion: W [K][N] fp32 -> W^T splits [N][K] bf16
template<int NS>
__global__ __launch_bounds__(256) void convW_kernel(
    const float* __restrict__ W,
    u16* __restrict__ o0, u16* __restrict__ o1, u16* __restrict__ o2)
{
    __shared__ float tile[64][65];
    int t = threadIdx.x;
    int n0 = blockIdx.x * 64, k0 = blockIdx.y * 64;
    int lr = t >> 4, lc4 = (t & 15) * 4;
    #pragma unroll
    for (int it = 0; it < 4; ++it) {
        float4 v = *(const float4*)(W + (size_t)(k0 + it * 16 + lr) * 1024 + n0 + lc4);
        tile[it * 16 + lr][lc4 + 0] = v.x;
        tile[it * 16 + lr][lc4 + 1] = v.y;
        tile[it * 16 + lr][lc4 + 2] = v.z;
        tile[it * 16 + lr][lc4 + 3] = v.w;
    }
    __syncthreads();
    #pragma unroll
    for (int it = 0; it < 4; ++it) {
        int ln = it * 16 + lr;                 // local n
        u16 hh[4], mm[4], ll[4];
        #pragma unroll
        for (int j = 0; j < 4; ++j) {
            float v = tile[lc4 + j][ln];
            u16 hv = bf16_rn(v); hh[j] = hv;
            if (NS == 3) {
                float r1 = v - bf16_tof(hv);
                u16 mv = bf16_rn(r1); mm[j] = mv;
                float r2 = r1 - bf16_tof(mv);
                ll[j] = bf16_rn(r2);
            }
        }
        size_t ob = ((size_t)(n0 + ln) * 1024 + k0 + lc4) >> 2;  // uint2 index
        ((uint2*)o0)[ob] = make_uint2(pack2(hh[0], hh[1]), pack2(hh[2], hh[3]));
        if (NS == 3) {
            ((uint2*)o1)[ob] = make_uint2(pack2(mm[0], mm[1]), pack2(mm[2], mm[3]));
            ((uint2*)o2)[ob] = make_uint2(pack2(ll[0], ll[1]), pack2(ll[2], ll[3]));
        }
    }
}

// ---------------- MFMA GEMM: C[M][1024] = A[M][1024] x W + bias
// A splits [M][1024] bf16 row-major; B = W^T splits [1024][1024] bf16 (n-major).
// TERMS=6: (h+m+l)x(h+m+l) keeping terms through 2^-18; TERMS=1: h*h.
template<int TERMS>
__global__ __launch_bounds__(256) void gemm_mfma_kernel(
    const u16* __restrict__ A0, const u16* __restrict__ A1, const u16* __restrict__ A2,
    const u16* __restrict__ B0, const u16* __restrict__ B1, const u16* __restrict__ B2,
    const float* __restrict__ bias, float* __restrict__ Cout)
{
    constexpr int NS = (TERMS == 6) ? 3 : 1;
    __shared__ u16 sA[NS][128][40];   // 32 k + 8 pad (80B rows: 2-way max on b128)
    __shared__ u16 sB[NS][128][40];

    int t = threadIdx.x;
    int m0 = blockIdx.y * 128, n0 = blockIdx.x * 128;
    int w = t >> 6, l = t & 63;
    int wy = w >> 1, wx = w & 1;

    f32x4 acc[4][4] = {};

    const u16* Ap[3] = {A0, A1, A2};
    const u16* Bp[3] = {B0, B1, B2};

    int r0 = t >> 2, q0 = t & 3;          // staging: chunk row/quarter
    int kb = (l >> 4) * 8;                // fragment k offset (shorts)
    int rA = wy * 64 + (l & 15);
    int rB = wx * 64 + (l & 15);

    #pragma unroll 1
    for (int k0 = 0; k0 < 1024; k0 += 32) {
        __syncthreads();
        #pragma unroll
        for (int s = 0; s < NS; ++s) {
            const u16* Ag = Ap[s] + (size_t)m0 * 1024 + k0;
            const u16* Bg = Bp[s] + (size_t)n0 * 1024 + k0;
            uint4 va0 = *(const uint4*)(Ag + (size_t)r0 * 1024 + q0 * 8);
            uint4 va1 = *(const uint4*)(Ag + (size_t)(64 + r0) * 1024 + q0 * 8);
            uint4 vb0 = *(const uint4*)(Bg + (size_t)r0 * 1024 + q0 * 8);
            uint4 vb1 = *(const uint4*)(Bg + (size_t)(64 + r0) * 1024 + q0 * 8);
            *(uint4*)&sA[s][r0][q0 * 8]      = va0;
            *(uint4*)&sA[s][64 + r0][q0 * 8] = va1;
            *(uint4*)&sB[s][r0][q0 * 8]      = vb0;
            *(uint4*)&sB[s][64 + r0][q0 * 8] = vb1;
        }
        __syncthreads();

        short8 bf[NS][4];
        #pragma unroll
        for (int s = 0; s < NS; ++s)
            #pragma unroll
            for (int j = 0; j < 4; ++j)
                bf[s][j] = *(const short8*)&sB[s][rB + j * 16][kb];

        #pragma unroll
        for (int i = 0; i < 4; ++i) {
            short8 af[NS];
            #pragma unroll
            for (int s = 0; s < NS; ++s) af[s] = *(const short8*)&sA[s][rA + i * 16][kb];
            #pragma unroll
            for (int j = 0; j < 4; ++j) {
                acc[i][j] = __builtin_amdgcn_mfma_f32_16x16x32_bf16(af[0], bf[0][j], acc[i][j], 0, 0, 0);
                if (TERMS == 6) {
                    acc[i][j] = __builtin_amdgcn_mfma_f32_16x16x32_bf16(af[0], bf[1][j], acc[i][j], 0, 0, 0);
                    acc[i][j] = __builtin_amdgcn_mfma_f32_16x16x32_bf16(af[1], bf[0][j], acc[i][j], 0, 0, 0);
                    acc[i][j] = __builtin_amdgcn_mfma_f32_16x16x32_bf16(af[0], bf[2][j], acc[i][j], 0, 0, 0);
                    acc[i][j] = __builtin_amdgcn_mfma_f32_16x16x32_bf16(af[1], bf[1][j], acc[i][j], 0, 0, 0);
                    acc[i][j] = __builtin_amdgcn_mfma_f32_16x16x32_bf16(af[2], bf[0][j], acc[i][j], 0, 0, 0);
                }
            }
        }
    }

    // epilogue: C row = m0+wy*64+i*16+(l>>4)*4+r, col = n0+wx*64+j*16+(l&15)
    #pragma unroll
    for (int i = 0; i < 4; ++i) {
        int row = m0 + wy * 64 + i * 16 + (l >> 4) * 4;
        #pragma unroll
        for (int j = 0; j < 4; ++j) {
            int col = n0 + wx * 64 + j * 16 + (l & 15);
            float bv = bias[col];
            #pragma unroll
            for (int r = 0; r < 4; ++r)
                Cout[(size_t)(row + r) * 1024 + col] = acc[i][j][r] + bv;
        }
    }
}

// ---------------- K1: c-path projections + LN  → cvec (3, B, D)
__global__ __launch_bounds__(256) void cproj_ln_kernel(
    const float* __restrict__ c,
    const float* __restrict__ W0, const float* __restrict__ b0,
    const float* __restrict__ g0, const float* __restrict__ be0,
    const float* __restrict__ W1, const float* __restrict__ b1,
    const float* __restrict__ g1, const float* __restrict__ be1,
    const float* __restrict__ W2, const float* __restrict__ b2,
    const float* __restrict__ g2, const float* __restrict__ be2,
    float* __restrict__ cvec)
{
    int b = blockIdx.x, which = blockIdx.y, t = threadIdx.x;
    const float *W, *bias, *g, *be;
    if (which == 0)      { W = W0; bias = b0; g = g0; be = be0; }
    else if (which == 1) { W = W1; bias = b1; g = g1; be = be1; }
    else                 { W = W2; bias = b2; g = g2; be = be2; }

    __shared__ float cs[CF_];
    __shared__ float red[18];
    cs[t] = c[b * CF_ + t];
    __syncthreads();

    float acc[4] = {0.f, 0.f, 0.f, 0.f};
    for (int k = 0; k < CF_; k++) {
        float cv = cs[k];
        const float* wr = W + (size_t)k * D_ + t;
        acc[0] = fmaf(cv, wr[0],   acc[0]);
        acc[1] = fmaf(cv, wr[256], acc[1]);
        acc[2] = fmaf(cv, wr[512], acc[2]);
        acc[3] = fmaf(cv, wr[768], acc[3]);
    }
    float x[4], s1 = 0.f, s2 = 0.f;
    #pragma unroll
    for (int i = 0; i < 4; i++) {
        x[i] = acc[i] + bias[t + 256 * i];
        s1 += x[i];
        s2 = fmaf(x[i], x[i], s2);
    }
    float2 ss = block_reduce_2(s1, s2, red);
    float mu  = ss.x * (1.0f / D_);
    float var = ss.y * (1.0f / D_) - mu * mu;
    float ve  = var + EPS_;
    float rs  = rsqrtf(ve);
    rs = rs * (1.5f - 0.5f * ve * rs * rs);
    #pragma unroll
    for (int i = 0; i < 4; i++) {
        int d = t + 256 * i;
        cvec[((size_t)which * B_ + b) * D_ + d] = (x[i] - mu) * rs * g[d] + be[d];
    }
}

// ---------------- K3: per-row LayerNorm + add c-vector (in place)
__global__ __launch_bounds__(256) void ln_add_kernel(
    float* __restrict__ qb,
    const float* __restrict__ g0, const float* __restrict__ be0,
    const float* __restrict__ g1, const float* __restrict__ be1,
    const float* __restrict__ g2, const float* __restrict__ be2,
    const float* __restrict__ cvec)
{
    int row = blockIdx.x, which = blockIdx.y, t = threadIdx.x;
    const float *g, *be;
    if (which == 0)      { g = g0; be = be0; }
    else if (which == 1) { g = g1; be = be1; }
    else                 { g = g2; be = be2; }

    __shared__ float red[18];
    float* p = qb + ((size_t)which * MROWS + row) * D_;
    const float* cv = cvec + ((size_t)which * B_ + (row / S_)) * D_;

    float4 x = *(const float4*)(p + t * 4);
    float s1 = x.x + x.y + x.z + x.w;
    float s2 = x.x * x.x + x.y * x.y + x.z * x.z + x.w * x.w;
    float2 ss = block_reduce_2(s1, s2, red);
    float mu  = ss.x * (1.0f / D_);
    float var = ss.y * (1.0f / D_) - mu * mu;
    float ve  = var + EPS_;
    float rs  = rsqrtf(ve);
    rs = rs * (1.5f - 0.5f * ve * rs * rs);

    float4 gv  = *(const float4*)(g  + t * 4);
    float4 bev = *(const float4*)(be + t * 4);
    float4 cvv = *(const float4*)(cv + t * 4);
    float4 o;
    o.x = (x.x - mu) * rs * gv.x + bev.x + cvv.x;
    o.y = (x.y - mu) * rs * gv.y + bev.y + cvv.y;
    o.z = (x.z - mu) * rs * gv.z + bev.z + cvv.z;
    o.w = (x.w - mu) * rs * gv.w + bev.w + cvv.w;
    *(float4*)(p + t * 4) = o;
}

// ---------------- K4: fused attention, tile-deferred softmax (unchanged from r2)
__global__ __launch_bounds__(512) void attn_kernel(
    const float* __restrict__ qb,
    float* __restrict__ attn_out,
    float* __restrict__ ctx)
{
    __shared__ float Qs[32][68];
    __shared__ float Ks[2][64][68];
    __shared__ unsigned short P[32][1024];
    __shared__ float Mj[32][16];
    __shared__ float Lj[32][16];
    __shared__ float Mfin[32], Linv[32];

    const float* q    = qb;
    const float* kmat = qb + (size_t)MROWS * D_;
    const float* v    = qb + 2 * (size_t)MROWS * D_;

    int i  = blockIdx.x;
    int sl = i >> 3;
    int g  = (i & 7) + 8 * (sl >> 5);
    int qt = sl & 31;
    int b  = g >> 4, h = g & 15;

    int t = threadIdx.x;
    int w = t >> 6, lane = t & 63;
    int qr0 = qt * 32;
    size_t base_bh = (size_t)b * S_ * D_ + (size_t)h * DK_;

    {
        int r = t >> 4, j4 = (t & 15) * 4;
        float4 qv = *(const float4*)(q + base_bh + (size_t)(qr0 + r) * D_ + j4);
        Qs[r][j4 + 0] = qv.x * SCALE_;
        Qs[r][j4 + 1] = qv.y * SCALE_;
        Qs[r][j4 + 2] = qv.z * SCALE_;
        Qs[r][j4 + 3] = qv.w * SCALE_;
    }
    #pragma unroll
    for (int i2 = 0; i2 < 2; ++i2) {
        int idx = i2 * 512 + t, row = idx >> 4, j4 = (idx & 15) * 4;
        *(float4*)&Ks[0][row][j4] =
            *(const float4*)(kmat + base_bh + (size_t)row * D_ + j4);
    }
    __syncthreads();

    #pragma unroll 1
    for (int j = 0; j < 16; ++j) {
        int cur = j & 1;
        float4 pf0, pf1;
        if (j < 15) {
            int idx0 = t,       row0 = idx0 >> 4, c0 = (idx0 & 15) * 4;
            int idx1 = 512 + t, row1 = idx1 >> 4, c1 = (idx1 & 15) * 4;
            pf0 = *(const float4*)(kmat + base_bh + (size_t)((j + 1) * 64 + row0) * D_ + c0);
            pf1 = *(const float4*)(kmat + base_bh + (size_t)((j + 1) * 64 + row1) * D_ + c1);
        }
        float4 kv[16];
        #pragma unroll
        for (int kk = 0; kk < 16; ++kk) kv[kk] = *(const float4*)&Ks[cur][lane][kk * 4];

        #pragma unroll
        for (int rr = 0; rr < 4; ++rr) {
            int r = w * 4 + rr;
            float a0 = 0.f, a1 = 0.f, a2 = 0.f, a3 = 0.f;
            #pragma unroll
            for (int kk = 0; kk < 16; ++kk) {
                float4 q4 = *(const float4*)&Qs[r][kk * 4];
                a0 = fmaf(q4.x, kv[kk].x, a0);
                a1 = fmaf(q4.y, kv[kk].y, a1);
                a2 = fmaf(q4.z, kv[kk].z, a2);
                a3 = fmaf(q4.w, kv[kk].w, a3);
            }
            float sv = (a0 + a1) + (a2 + a3);
            float m  = wave_max64(sv);
            float p  = __expf(sv - m);
            float lsum = wave_sum64(p);
            unsigned u = __float_as_uint(p);
            u += 0x7fffu + ((u >> 16) & 1u);
            P[r][j * 64 + lane] = (unsigned short)(u >> 16);
            if (lane == 0) { Mj[r][j] = m; Lj[r][j] = lsum; }
        }
        if (j < 15) {
            int idx0 = t,       row0 = idx0 >> 4, c0 = (idx0 & 15) * 4;
            int idx1 = 512 + t, row1 = idx1 >> 4, c1 = (idx1 & 15) * 4;
            *(float4*)&Ks[1 - cur][row0][c0] = pf0;
            *(float4*)&Ks[1 - cur][row1][c1] = pf1;
            __syncthreads();
        }
    }
    __syncthreads();

    if (t < 32) {
        float m = -3.4e38f;
        #pragma unroll
        for (int j2 = 0; j2 < 16; ++j2) m = fmaxf(m, Mj[t][j2]);
        float L = 0.f;
        #pragma unroll
        for (int j2 = 0; j2 < 16; ++j2) L += Lj[t][j2] * __expf(Mj[t][j2] - m);
        Mfin[t] = m;
        Linv[t] = 1.0f / L;
    }
    __syncthreads();

    {
        float* abase = attn_out + (((size_t)b * H_ + h) * S_ + qr0) * S_;
        #pragma unroll
        for (int rr = 0; rr < 4; ++rr) {
            int r = w * 4 + rr;
            float mf = Mfin[r], li = Linv[r];
            #pragma unroll
            for (int chunk = 0; chunk < 4; ++chunk) {
                int cc = chunk * 256 + lane * 4;
                int jidx = cc >> 6;
                float scl = __expf(Mj[r][jidx] - mf) * li;
                uint2 pu = *(const uint2*)&P[r][cc];
                float4 o;
                o.x = __uint_as_float(pu.x << 16) * scl;
                o.y = __uint_as_float(pu.x & 0xffff0000u) * scl;
                o.z = __uint_as_float(pu.y << 16) * scl;
                o.w = __uint_as_float(pu.y & 0xffff0000u) * scl;
                *(float4*)(abase + (size_t)r * S_ + cc) = o;
            }
        }
    }

    float acc[4] = {0.f, 0.f, 0.f, 0.f};
    const float* vb = v + base_bh + lane;
    #pragma unroll 1
    for (int j = 0; j < 16; ++j) {
        float sc4[4];
        #pragma unroll
        for (int rr = 0; rr < 4; ++rr) {
            int r = w * 4 + rr;
            sc4[rr] = __expf(Mj[r][j] - Mfin[r]);
        }
        const float* vj = vb + (size_t)(j * 64) * D_;
        float ta[4] = {0.f, 0.f, 0.f, 0.f};
        float v0 = vj[0], v1 = vj[D_], v2 = vj[2 * D_], v3 = vj[3 * D_];
        #pragma unroll
        for (int ch = 0; ch < 16; ++ch) {
            float n0 = 0.f, n1 = 0.f, n2 = 0.f, n3 = 0.f;
            if (ch < 15) {
                const float* vn = vj + (size_t)(ch * 4 + 4) * D_;
                n0 = vn[0]; n1 = vn[D_]; n2 = vn[2 * D_]; n3 = vn[3 * D_];
            }
            #pragma unroll
            for (int rr = 0; rr < 4; ++rr) {
                int r = w * 4 + rr;
                uint2 pu = *(const uint2*)&P[r][j * 64 + ch * 4];
                ta[rr] = fmaf(__uint_as_float(pu.x << 16),          v0, ta[rr]);
                ta[rr] = fmaf(__uint_as_float(pu.x & 0xffff0000u),  v1, ta[rr]);
                ta[rr] = fmaf(__uint_as_float(pu.y << 16),          v2, ta[rr]);
                ta[rr] = fmaf(__uint_as_float(pu.y & 0xffff0000u),  v3, ta[rr]);
            }
            v0 = n0; v1 = n1; v2 = n2; v3 = n3;
        }
        #pragma unroll
        for (int rr = 0; rr < 4; ++rr) acc[rr] = fmaf(ta[rr], sc4[rr], acc[rr]);
    }
    #pragma unroll
    for (int rr = 0; rr < 4; ++rr) {
        int r = w * 4 + rr;
        ctx[base_bh + (size_t)(qr0 + r) * D_ + lane] = acc[rr] * Linv[r];
    }
}

// ---------------- launch
extern "C" void kernel_launch(void* const* d_in, const int* in_sizes, int n_in,
                              void* d_out, int out_size, void* d_ws, size_t ws_size,
                              hipStream_t stream) {
    const float* Q    = (const float*)d_in[0];
    const float* c    = (const float*)d_in[1];
    const float* Wq   = (const float*)d_in[2];
    const float* bq   = (const float*)d_in[3];
    const float* Wk   = (const float*)d_in[4];
    const float* bk   = (const float*)d_in[5];
    const float* Wv   = (const float*)d_in[6];
    const float* bv   = (const float*)d_in[7];
    const float* Wcq  = (const float*)d_in[8];
    const float* bcq  = (const float*)d_in[9];
    const float* Wck  = (const float*)d_in[10];
    const float* bck  = (const float*)d_in[11];
    const float* Wcv  = (const float*)d_in[12];
    const float* bcv  = (const float*)d_in[13];
    const float* g_q  = (const float*)d_in[14];
    const float* be_q = (const float*)d_in[15];
    const float* g_qc = (const float*)d_in[16];
    const float* be_qc= (const float*)d_in[17];
    const float* g_k  = (const float*)d_in[18];
    const float* be_k = (const float*)d_in[19];
    const float* g_kc = (const float*)d_in[20];
    const float* be_kc= (const float*)d_in[21];
    const float* g_v  = (const float*)d_in[22];
    const float* be_v = (const float*)d_in[23];
    const float* g_vc = (const float*)d_in[24];
    const float* be_vc= (const float*)d_in[25];
    const float* Wo   = (const float*)d_in[26];
    const float* bo   = (const float*)d_in[27];

    const size_t MD = (size_t)MROWS * D_;     // 8388608
    const size_t MK = (size_t)D_ * D_;        // 1048576
    float* f0   = (float*)d_ws;
    float* qb   = f0;                 // 3*MD fp32 (q|k|v)
    float* ctx  = f0 + 3 * MD;        // MD
    float* cvec = f0 + 4 * MD;        // 3*B*D = 24576

    u16* U   = (u16*)(f0 + 4 * MD + 24576);
    u16* Qh  = U;
    u16* Qm  = U + MD;
    u16* Ql  = U + 2 * MD;
    u16* Wqt = U + 3 * MD;            // h,m,l consecutive (3*MK)
    u16* Wkt = Wqt + 3 * MK;
    u16* Wvt = Wkt + 3 * MK;          // 1*MK
    u16* Wot = Wvt + MK;              // 1*MK
    u16* Ch  = (u16*)qb;              // overlay: q fp32 dead after attn

    float* out_p  = (float*)d_out;
    float* attn_p = (float*)d_out + MD;

    // converts
    convA_kernel<3><<<2048, 256, 0, stream>>>(Q, Qh, Qm, Ql, (int)(MD / 4));
    convW_kernel<3><<<dim3(16, 16), 256, 0, stream>>>(Wq, Wqt, Wqt + MK, Wqt + 2 * MK);
    convW_kernel<3><<<dim3(16, 16), 256, 0, stream>>>(Wk, Wkt, Wkt + MK, Wkt + 2 * MK);
    convW_kernel<1><<<dim3(16, 16), 256, 0, stream>>>(Wv, Wvt, nullptr, nullptr);
    convW_kernel<1><<<dim3(16, 16), 256, 0, stream>>>(Wo, Wot, nullptr, nullptr);

    // c-path
    cproj_ln_kernel<<<dim3(B_, 3), 256, 0, stream>>>(
        c, Wcq, bcq, g_qc, be_qc, Wck, bck, g_kc, be_kc, Wcv, bcv, g_vc, be_vc, cvec);

    // projections: q,k (6-term fp32-equivalent), v (1-term bf16)
    dim3 ggrid(1024 / 128, MROWS / 128);
    gemm_mfma_kernel<6><<<ggrid, 256, 0, stream>>>(Qh, Qm, Ql, Wqt, Wqt + MK, Wqt + 2 * MK, bq, qb);
    gemm_mfma_kernel<6><<<ggrid, 256, 0, stream>>>(Qh, Qm, Ql, Wkt, Wkt + MK, Wkt + 2 * MK, bk, qb + MD);
    gemm_mfma_kernel<1><<<ggrid, 256, 0, stream>>>(Qh, nullptr, nullptr, Wvt, nullptr, nullptr, bv, qb + 2 * MD);

    // LN + c-vector add
    ln_add_kernel<<<dim3(MROWS, 3), 256, 0, stream>>>(
        qb, g_q, be_q, g_k, be_k, g_v, be_v, cvec);

    // attention
    attn_kernel<<<dim3(4096), 512, 0, stream>>>(qb, attn_p, ctx);

    // out projection: ctx -> bf16, 1-term GEMM
    convA_kernel<1><<<2048, 256, 0, stream>>>(ctx, Ch, nullptr, nullptr, (int)(MD / 4));
    gemm_mfma_kernel<1><<<ggrid, 256, 0, stream>>>(Ch, nullptr, nullptr, Wot, nullptr, nullptr, bo, out_p);
}

// Round 6
// 1413.704 us; speedup vs baseline: 3.9388x; 1.7598x over previous
//
#include <hip/hip_runtime.h>

#define B_   8
#define S_   1024
#define D_   1024
#define H_   16
#define DK_  64
#define CF_  256
#define MROWS (B_*S_)          // 8192
#define SCALE_ 512.0f
#define EPS_ 1e-5f

typedef unsigned short u16;
typedef __attribute__((ext_vector_type(8))) short short8;   // 8 bf16 = 4 VGPR
typedef __attribute__((ext_vector_type(4))) float f32x4;

#define MFMA16(a, b, c) __builtin_amdgcn_mfma_f32_16x16x32_bf16((a), (b), (c), 0, 0, 0)

__device__ __forceinline__ u16 bf16_rn(float x) {
    unsigned u = __float_as_uint(x);
    u += 0x7fffu + ((u >> 16) & 1u);
    return (u16)(u >> 16);
}
__device__ __forceinline__ float bf16_tof(u16 h) {
    return __uint_as_float(((unsigned)h) << 16);
}
__device__ __forceinline__ unsigned pack2(u16 a, u16 b) {
    return (unsigned)a | ((unsigned)b << 16);
}
__device__ __forceinline__ void split3(float v, u16& h, u16& m, u16& l) {
    h = bf16_rn(v);
    float r1 = v - bf16_tof(h);
    m = bf16_rn(r1);
    float r2 = r1 - bf16_tof(m);
    l = bf16_rn(r2);
}

// ---------------- block reduce (256 thr): sum of two values
__device__ __forceinline__ float2 block_reduce_2(float s1, float s2, float* red) {
    #pragma unroll
    for (int off = 32; off; off >>= 1) {
        s1 += __shfl_xor(s1, off);
        s2 += __shfl_xor(s2, off);
    }
    int wid = threadIdx.x >> 6, lane = threadIdx.x & 63;
    if (lane == 0) { red[wid] = s1; red[8 + wid] = s2; }
    __syncthreads();
    if (threadIdx.x == 0) {
        float a = 0.f, b = 0.f;
        for (int i = 0; i < 4; i++) { a += red[i]; b += red[8 + i]; }
        red[16] = a; red[17] = b;
    }
    __syncthreads();
    float2 r = make_float2(red[16], red[17]);
    __syncthreads();
    return r;
}

// ---------------- conversion: A-side split (NS = 3 or 1), row-major [M][1024]
template<int NS>
__global__ __launch_bounds__(256) void convA_kernel(
    const float* __restrict__ in, u16* __restrict__ h,
    u16* __restrict__ m, u16* __restrict__ l, int n4)
{
    int i = blockIdx.x * blockDim.x + threadIdx.x;
    int stride = gridDim.x * blockDim.x;
    for (; i < n4; i += stride) {
        float4 x = ((const float4*)in)[i];
        float xs[4] = {x.x, x.y, x.z, x.w};
        u16 hh[4], mm[4], ll[4];
        #pragma unroll
        for (int j = 0; j < 4; ++j) {
            float v = xs[j];
            u16 hv = bf16_rn(v); hh[j] = hv;
            if (NS == 3) {
                float r1 = v - bf16_tof(hv);
                u16 mv = bf16_rn(r1); mm[j] = mv;
                ll[j] = bf16_rn(r1 - bf16_tof(mv));
            }
        }
        ((uint2*)h)[i] = make_uint2(pack2(hh[0], hh[1]), pack2(hh[2], hh[3]));
        if (NS == 3) {
            ((uint2*)m)[i] = make_uint2(pack2(mm[0], mm[1]), pack2(mm[2], mm[3]));
            ((uint2*)l)[i] = make_uint2(pack2(ll[0], ll[1]), pack2(ll[2], ll[3]));
        }
    }
}

// ---------------- conversion: W [K][N] fp32 -> W^T splits [N][K] bf16
template<int NS>
__global__ __launch_bounds__(256) void convW_kernel(
    const float* __restrict__ W,
    u16* __restrict__ o0, u16* __restrict__ o1, u16* __restrict__ o2)
{
    __shared__ float tile[64][65];
    int t = threadIdx.x;
    int n0 = blockIdx.x * 64, k0 = blockIdx.y * 64;
    int lr = t >> 4, lc4 = (t & 15) * 4;
    #pragma unroll
    for (int it = 0; it < 4; ++it) {
        float4 v = *(const float4*)(W + (size_t)(k0 + it * 16 + lr) * 1024 + n0 + lc4);
        tile[it * 16 + lr][lc4 + 0] = v.x;
        tile[it * 16 + lr][lc4 + 1] = v.y;
        tile[it * 16 + lr][lc4 + 2] = v.z;
        tile[it * 16 + lr][lc4 + 3] = v.w;
    }
    __syncthreads();
    #pragma unroll
    for (int it = 0; it < 4; ++it) {
        int ln = it * 16 + lr;
        u16 hh[4], mm[4], ll[4];
        #pragma unroll
        for (int j = 0; j < 4; ++j) {
            float v = tile[lc4 + j][ln];
            u16 hv = bf16_rn(v); hh[j] = hv;
            if (NS == 3) {
                float r1 = v - bf16_tof(hv);
                u16 mv = bf16_rn(r1); mm[j] = mv;
                ll[j] = bf16_rn(r1 - bf16_tof(mv));
            }
        }
        size_t ob = ((size_t)(n0 + ln) * 1024 + k0 + lc4) >> 2;
        ((uint2*)o0)[ob] = make_uint2(pack2(hh[0], hh[1]), pack2(hh[2], hh[3]));
        if (NS == 3) {
            ((uint2*)o1)[ob] = make_uint2(pack2(mm[0], mm[1]), pack2(mm[2], mm[3]));
            ((uint2*)o2)[ob] = make_uint2(pack2(ll[0], ll[1]), pack2(ll[2], ll[3]));
        }
    }
}

// ---------------- MFMA GEMM: C[M][1024] = A[M][1024] x W + bias (r4-verified)
template<int TERMS>
__global__ __launch_bounds__(256) void gemm_mfma_kernel(
    const u16* __restrict__ A0, const u16* __restrict__ A1, const u16* __restrict__ A2,
    const u16* __restrict__ B0, const u16* __restrict__ B1, const u16* __restrict__ B2,
    const float* __restrict__ bias, float* __restrict__ Cout)
{
    constexpr int NS = (TERMS == 6) ? 3 : 1;
    __shared__ u16 sA[NS][128][40];
    __shared__ u16 sB[NS][128][40];

    int t = threadIdx.x;
    int m0 = blockIdx.y * 128, n0 = blockIdx.x * 128;
    int w = t >> 6, l = t & 63;
    int wy = w >> 1, wx = w & 1;

    f32x4 acc[4][4] = {};

    const u16* Ap[3] = {A0, A1, A2};
    const u16* Bp[3] = {B0, B1, B2};

    int r0 = t >> 2, q0 = t & 3;
    int kb = (l >> 4) * 8;
    int rA = wy * 64 + (l & 15);
    int rB = wx * 64 + (l & 15);

    #pragma unroll 1
    for (int k0 = 0; k0 < 1024; k0 += 32) {
        __syncthreads();
        #pragma unroll
        for (int s = 0; s < NS; ++s) {
            const u16* Ag = Ap[s] + (size_t)m0 * 1024 + k0;
            const u16* Bg = Bp[s] + (size_t)n0 * 1024 + k0;
            uint4 va0 = *(const uint4*)(Ag + (size_t)r0 * 1024 + q0 * 8);
            uint4 va1 = *(const uint4*)(Ag + (size_t)(64 + r0) * 1024 + q0 * 8);
            uint4 vb0 = *(const uint4*)(Bg + (size_t)r0 * 1024 + q0 * 8);
            uint4 vb1 = *(const uint4*)(Bg + (size_t)(64 + r0) * 1024 + q0 * 8);
            *(uint4*)&sA[s][r0][q0 * 8]      = va0;
            *(uint4*)&sA[s][64 + r0][q0 * 8] = va1;
            *(uint4*)&sB[s][r0][q0 * 8]      = vb0;
            *(uint4*)&sB[s][64 + r0][q0 * 8] = vb1;
        }
        __syncthreads();

        short8 bf[NS][4];
        #pragma unroll
        for (int s = 0; s < NS; ++s)
            #pragma unroll
            for (int j = 0; j < 4; ++j)
                bf[s][j] = *(const short8*)&sB[s][rB + j * 16][kb];

        #pragma unroll
        for (int i = 0; i < 4; ++i) {
            short8 af[NS];
            #pragma unroll
            for (int s = 0; s < NS; ++s) af[s] = *(const short8*)&sA[s][rA + i * 16][kb];
            #pragma unroll
            for (int j = 0; j < 4; ++j) {
                acc[i][j] = MFMA16(af[0], bf[0][j], acc[i][j]);
                if (TERMS == 6) {
                    acc[i][j] = MFMA16(af[0], bf[1][j], acc[i][j]);
                    acc[i][j] = MFMA16(af[1], bf[0][j], acc[i][j]);
                    acc[i][j] = MFMA16(af[0], bf[2][j], acc[i][j]);
                    acc[i][j] = MFMA16(af[1], bf[1][j], acc[i][j]);
                    acc[i][j] = MFMA16(af[2], bf[0][j], acc[i][j]);
                }
            }
        }
    }

    #pragma unroll
    for (int i = 0; i < 4; ++i) {
        int row = m0 + wy * 64 + i * 16 + (l >> 4) * 4;
        #pragma unroll
        for (int j = 0; j < 4; ++j) {
            int col = n0 + wx * 64 + j * 16 + (l & 15);
            float bv = bias[col];
            #pragma unroll
            for (int r = 0; r < 4; ++r)
                Cout[(size_t)(row + r) * 1024 + col] = acc[i][j][r] + bv;
        }
    }
}

// ---------------- K1: c-path projections + LN  → cvec (3, B, D)
__global__ __launch_bounds__(256) void cproj_ln_kernel(
    const float* __restrict__ c,
    const float* __restrict__ W0, const float* __restrict__ b0,
    const float* __restrict__ g0, const float* __restrict__ be0,
    const float* __restrict__ W1, const float* __restrict__ b1,
    const float* __restrict__ g1, const float* __restrict__ be1,
    const float* __restrict__ W2, const float* __restrict__ b2,
    const float* __restrict__ g2, const float* __restrict__ be2,
    float* __restrict__ cvec)
{
    int b = blockIdx.x, which = blockIdx.y, t = threadIdx.x;
    const float *W, *bias, *g, *be;
    if (which == 0)      { W = W0; bias = b0; g = g0; be = be0; }
    else if (which == 1) { W = W1; bias = b1; g = g1; be = be1; }
    else                 { W = W2; bias = b2; g = g2; be = be2; }

    __shared__ float cs[CF_];
    __shared__ float red[18];
    cs[t] = c[b * CF_ + t];
    __syncthreads();

    float acc[4] = {0.f, 0.f, 0.f, 0.f};
    for (int k = 0; k < CF_; k++) {
        float cv = cs[k];
        const float* wr = W + (size_t)k * D_ + t;
        acc[0] = fmaf(cv, wr[0],   acc[0]);
        acc[1] = fmaf(cv, wr[256], acc[1]);
        acc[2] = fmaf(cv, wr[512], acc[2]);
        acc[3] = fmaf(cv, wr[768], acc[3]);
    }
    float x[4], s1 = 0.f, s2 = 0.f;
    #pragma unroll
    for (int i = 0; i < 4; i++) {
        x[i] = acc[i] + bias[t + 256 * i];
        s1 += x[i];
        s2 = fmaf(x[i], x[i], s2);
    }
    float2 ss = block_reduce_2(s1, s2, red);
    float mu  = ss.x * (1.0f / D_);
    float var = ss.y * (1.0f / D_) - mu * mu;
    float ve  = var + EPS_;
    float rs  = rsqrtf(ve);
    rs = rs * (1.5f - 0.5f * ve * rs * rs);
    #pragma unroll
    for (int i = 0; i < 4; i++) {
        int d = t + 256 * i;
        cvec[((size_t)which * B_ + b) * D_ + d] = (x[i] - mu) * rs * g[d] + be[d];
    }
}

// ---------------- K3: per-row LN + c-add, then emit head-major bf16 splits
// q: 3 splits, SCALE folded; k: 3 splits; v: 1 (bf16)
__global__ __launch_bounds__(256) void ln_split_kernel(
    const float* __restrict__ pb,               // (3, MROWS, D) proj outputs
    const float* __restrict__ g0, const float* __restrict__ be0,
    const float* __restrict__ g1, const float* __restrict__ be1,
    const float* __restrict__ g2, const float* __restrict__ be2,
    const float* __restrict__ cvec,             // (3, B, D)
    u16* __restrict__ qh, u16* __restrict__ qm, u16* __restrict__ ql,
    u16* __restrict__ kh, u16* __restrict__ km, u16* __restrict__ kl,
    u16* __restrict__ vh)
{
    int row = blockIdx.x, which = blockIdx.y, t = threadIdx.x;
    const float *g, *be;
    if (which == 0)      { g = g0; be = be0; }
    else if (which == 1) { g = g1; be = be1; }
    else                 { g = g2; be = be2; }

    __shared__ float red[18];
    const float* p  = pb + ((size_t)which * MROWS + row) * D_;
    const float* cv = cvec + ((size_t)which * B_ + (row >> 10)) * D_;

    float4 x = *(const float4*)(p + t * 4);
    float s1 = x.x + x.y + x.z + x.w;
    float s2 = x.x * x.x + x.y * x.y + x.z * x.z + x.w * x.w;
    float2 ss = block_reduce_2(s1, s2, red);
    float mu  = ss.x * (1.0f / D_);
    float var = ss.y * (1.0f / D_) - mu * mu;
    float ve  = var + EPS_;
    float rs  = rsqrtf(ve);
    rs = rs * (1.5f - 0.5f * ve * rs * rs);

    int d0 = t * 4;
    float4 gv  = *(const float4*)(g  + d0);
    float4 bev = *(const float4*)(be + d0);
    float4 cvv = *(const float4*)(cv + d0);
    float y[4];
    y[0] = (x.x - mu) * rs * gv.x + bev.x + cvv.x;
    y[1] = (x.y - mu) * rs * gv.y + bev.y + cvv.y;
    y[2] = (x.z - mu) * rs * gv.z + bev.z + cvv.z;
    y[3] = (x.w - mu) * rs * gv.w + bev.w + cvv.w;

    int b = row >> 10, s = row & 1023;
    int h = d0 >> 6, dk = d0 & 63;
    size_t ha = (((size_t)(b * 16 + h)) * 1024 + s) * 64 + dk;

    if (which == 0) {
        u16 hh[4], mm[4], ll[4];
        #pragma unroll
        for (int i = 0; i < 4; ++i) split3(y[i] * SCALE_, hh[i], mm[i], ll[i]);
        *(uint2*)(qh + ha) = make_uint2(pack2(hh[0], hh[1]), pack2(hh[2], hh[3]));
        *(uint2*)(qm + ha) = make_uint2(pack2(mm[0], mm[1]), pack2(mm[2], mm[3]));
        *(uint2*)(ql + ha) = make_uint2(pack2(ll[0], ll[1]), pack2(ll[2], ll[3]));
    } else if (which == 1) {
        u16 hh[4], mm[4], ll[4];
        #pragma unroll
        for (int i = 0; i < 4; ++i) split3(y[i], hh[i], mm[i], ll[i]);
        *(uint2*)(kh + ha) = make_uint2(pack2(hh[0], hh[1]), pack2(hh[2], hh[3]));
        *(uint2*)(km + ha) = make_uint2(pack2(mm[0], mm[1]), pack2(mm[2], mm[3]));
        *(uint2*)(kl + ha) = make_uint2(pack2(ll[0], ll[1]), pack2(ll[2], ll[3]));
    } else {
        u16 hh[4];
        #pragma unroll
        for (int i = 0; i < 4; ++i) hh[i] = bf16_rn(y[i]);
        *(uint2*)(vh + ha) = make_uint2(pack2(hh[0], hh[1]), pack2(hh[2], hh[3]));
    }
}

// ---------------- V transpose: vh [g][s][dk] -> vt [g][dk][s]
__global__ __launch_bounds__(256) void vtrans_kernel(
    const u16* __restrict__ vh, u16* __restrict__ vt)
{
    __shared__ u16 tile[64][72];
    int g = blockIdx.x, st = blockIdx.y, t = threadIdx.x;
    const u16* src = vh + ((size_t)g * 1024 + st * 64) * 64;
    int row = t & 63, seg = t >> 6;
    *(uint4*)&tile[row][seg * 16]     = *(const uint4*)(src + row * 64 + seg * 16);
    *(uint4*)&tile[row][seg * 16 + 8] = *(const uint4*)(src + row * 64 + seg * 16 + 8);
    __syncthreads();
    u16* dst = vt + (size_t)g * 65536 + st * 64;
    int dk = t & 63, ss = t >> 6;
    u16 tmp[16];
    #pragma unroll
    for (int j = 0; j < 16; ++j) tmp[j] = tile[ss * 16 + j][dk];
    uint4 a, b2;
    a.x  = pack2(tmp[0],  tmp[1]);  a.y  = pack2(tmp[2],  tmp[3]);
    a.z  = pack2(tmp[4],  tmp[5]);  a.w  = pack2(tmp[6],  tmp[7]);
    b2.x = pack2(tmp[8],  tmp[9]);  b2.y = pack2(tmp[10], tmp[11]);
    b2.z = pack2(tmp[12], tmp[13]); b2.w = pack2(tmp[14], tmp[15]);
    *(uint4*)(dst + (size_t)dk * 1024 + ss * 16)     = a;
    *(uint4*)(dst + (size_t)dk * 1024 + ss * 16 + 8) = b2;
}

// ---------------- K4: MFMA attention (b,h,qtile32), 8 waves
// wave w: QK^T cols w*128..+127 (8 tiles of 16); PV tile (rt=w>>2, dkt=w&3)
__global__ __launch_bounds__(512, 2) void attn_mfma_kernel(
    const u16* __restrict__ qh, const u16* __restrict__ qm, const u16* __restrict__ ql,
    const u16* __restrict__ kh, const u16* __restrict__ km, const u16* __restrict__ kl,
    const u16* __restrict__ vt,
    float* __restrict__ attn_out,   // (B,H,S,S)
    u16* __restrict__ Ch)           // (MROWS,1024) bf16 ctx for Wo GEMM
{
    __shared__ u16 P[32][1032];     // exp(s - M) bf16; row stride 2064B (16B-mult)
    __shared__ float Mpart[8][32];
    __shared__ float Spart[8][32];
    __shared__ float LinvS[32];

    int i  = blockIdx.x;
    int sl = i >> 3;
    int g  = (i & 7) + 8 * (sl >> 5);   // g = b*16+h; 32 q-tiles of one g per XCD
    int qt = sl & 31;
    int b  = g >> 4, h = g & 15;

    int t = threadIdx.x, w = t >> 6, l = t & 63;
    int l15 = l & 15, l4 = l >> 4;
    int qr0 = qt * 32;
    size_t hb = (size_t)g * 65536;      // head base (shorts) in [g][s][dk]

    // ---- hoist Q A-fragments: [split][rt][ks]
    short8 qf[3][2][2];
    {
        size_t qoff = hb + (size_t)(qr0 + l15) * 64 + l4 * 8;
        #pragma unroll
        for (int rt = 0; rt < 2; ++rt)
            #pragma unroll
            for (int ks = 0; ks < 2; ++ks) {
                size_t o = qoff + rt * (16 * 64) + ks * 32;
                qf[0][rt][ks] = *(const short8*)(qh + o);
                qf[1][rt][ks] = *(const short8*)(qm + o);
                qf[2][rt][ks] = *(const short8*)(ql + o);
            }
    }

    // ---- QK^T: acc[rt][ct], score row = rt*16+l4*4+r, col = w*128+ct*16+l15
    f32x4 acc[2][8] = {};
    {
        size_t kb0 = hb + (size_t)(w * 128 + l15) * 64 + l4 * 8;
        #pragma unroll
        for (int ct = 0; ct < 8; ++ct) {
            #pragma unroll
            for (int ks = 0; ks < 2; ++ks) {
                size_t ko = kb0 + ct * (16 * 64) + ks * 32;
                short8 bh_ = *(const short8*)(kh + ko);
                short8 bm_ = *(const short8*)(km + ko);
                short8 bl_ = *(const short8*)(kl + ko);
                #pragma unroll
                for (int rt = 0; rt < 2; ++rt) {
                    f32x4 a = acc[rt][ct];
                    a = MFMA16(qf[0][rt][ks], bh_, a);
                    a = MFMA16(qf[0][rt][ks], bm_, a);
                    a = MFMA16(qf[1][rt][ks], bh_, a);
                    a = MFMA16(qf[0][rt][ks], bl_, a);
                    a = MFMA16(qf[1][rt][ks], bm_, a);
                    a = MFMA16(qf[2][rt][ks], bh_, a);
                    acc[rt][ct] = a;
                }
            }
        }
    }

    // ---- row max: in-lane over 8 tiles, shfl over 16 col-lanes, LDS over waves
    float rmax[2][4];
    #pragma unroll
    for (int rt = 0; rt < 2; ++rt)
        #pragma unroll
        for (int r = 0; r < 4; ++r) {
            float m = acc[rt][0][r];
            #pragma unroll
            for (int ct = 1; ct < 8; ++ct) m = fmaxf(m, acc[rt][ct][r]);
            #pragma unroll
            for (int off = 1; off < 16; off <<= 1) m = fmaxf(m, __shfl_xor(m, off));
            rmax[rt][r] = m;
        }
    if (l15 == 0) {
        #pragma unroll
        for (int rt = 0; rt < 2; ++rt)
            #pragma unroll
            for (int r = 0; r < 4; ++r)
                Mpart[w][rt * 16 + l4 * 4 + r] = rmax[rt][r];
    }
    __syncthreads();
    #pragma unroll
    for (int rt = 0; rt < 2; ++rt)
        #pragma unroll
        for (int r = 0; r < 4; ++r) {
            int row = rt * 16 + l4 * 4 + r;
            float m = Mpart[0][row];
            #pragma unroll
            for (int wv = 1; wv < 8; ++wv) m = fmaxf(m, Mpart[wv][row]);
            rmax[rt][r] = m;
        }

    // ---- exp + row sum
    float rsum[2][4] = {};
    #pragma unroll
    for (int rt = 0; rt < 2; ++rt)
        #pragma unroll
        for (int ct = 0; ct < 8; ++ct)
            #pragma unroll
            for (int r = 0; r < 4; ++r) {
                float p = __expf(acc[rt][ct][r] - rmax[rt][r]);
                acc[rt][ct][r] = p;
                rsum[rt][r] += p;
            }
    #pragma unroll
    for (int rt = 0; rt < 2; ++rt)
        #pragma unroll
        for (int r = 0; r < 4; ++r) {
            float s = rsum[rt][r];
            #pragma unroll
            for (int off = 1; off < 16; off <<= 1) s += __shfl_xor(s, off);
            rsum[rt][r] = s;
        }
    if (l15 == 0) {
        #pragma unroll
        for (int rt = 0; rt < 2; ++rt)
            #pragma unroll
            for (int r = 0; r < 4; ++r)
                Spart[w][rt * 16 + l4 * 4 + r] = rsum[rt][r];
    }
    __syncthreads();
    if (w == 0 && l15 == 0) {
        #pragma unroll
        for (int rt = 0; rt < 2; ++rt)
            #pragma unroll
            for (int r = 0; r < 4; ++r) {
                int row = rt * 16 + l4 * 4 + r;
                float s = 0.f;
                #pragma unroll
                for (int wv = 0; wv < 8; ++wv) s += Spart[wv][row];
                LinvS[row] = 1.0f / s;
            }
    }
    // ---- store P (bf16)
    #pragma unroll
    for (int rt = 0; rt < 2; ++rt)
        #pragma unroll
        for (int ct = 0; ct < 8; ++ct)
            #pragma unroll
            for (int r = 0; r < 4; ++r)
                P[rt * 16 + l4 * 4 + r][w * 128 + ct * 16 + l15] = bf16_rn(acc[rt][ct][r]);
    __syncthreads();

    // ---- write attn_out (coalesced float4 from LDS P)
    {
        float* abase = attn_out + ((size_t)g * 1024 + qr0) * 1024;
        #pragma unroll
        for (int it = 0; it < 8; ++it) {
            int idx = it * 512 + t;
            int row = idx >> 7;
            int c8  = (idx & 127) * 8;
            float li = LinvS[row];
            uint4 pu = *(const uint4*)&P[row][c8];
            float4 o0, o1;
            o0.x = __uint_as_float(pu.x << 16) * li;
            o0.y = __uint_as_float(pu.x & 0xffff0000u) * li;
            o0.z = __uint_as_float(pu.y << 16) * li;
            o0.w = __uint_as_float(pu.y & 0xffff0000u) * li;
            o1.x = __uint_as_float(pu.z << 16) * li;
            o1.y = __uint_as_float(pu.z & 0xffff0000u) * li;
            o1.z = __uint_as_float(pu.w << 16) * li;
            o1.w = __uint_as_float(pu.w & 0xffff0000u) * li;
            float* dst = abase + (size_t)row * 1024 + c8;
            *(float4*)dst       = o0;
            *(float4*)(dst + 4) = o1;
        }
    }

    // ---- PV: wave tile (rt = w>>2, dkt = w&3); A = P (LDS), B = vt (global)
    {
        int rt = w >> 2, dkt = w & 3;
        f32x4 pacc = {};
        const u16* vrow = vt + (size_t)g * 65536 + (size_t)(dkt * 16 + l15) * 1024 + l4 * 8;
        const u16* prow = &P[rt * 16 + l15][l4 * 8];
        #pragma unroll 8
        for (int ks = 0; ks < 32; ++ks) {
            short8 pa = *(const short8*)(prow + ks * 32);
            short8 vb = *(const short8*)(vrow + ks * 32);
            pacc = MFMA16(pa, vb, pacc);
        }
        int col = h * 64 + dkt * 16 + l15;
        #pragma unroll
        for (int r = 0; r < 4; ++r) {
            int lrow = rt * 16 + l4 * 4 + r;
            float val = pacc[r] * LinvS[lrow];
            Ch[(size_t)(b * 1024 + qr0 + lrow) * 1024 + col] = bf16_rn(val);
        }
    }
}

// ---------------- launch
extern "C" void kernel_launch(void* const* d_in, const int* in_sizes, int n_in,
                              void* d_out, int out_size, void* d_ws, size_t ws_size,
                              hipStream_t stream) {
    const float* Q    = (const float*)d_in[0];
    const float* c    = (const float*)d_in[1];
    const float* Wq   = (const float*)d_in[2];
    const float* bq   = (const float*)d_in[3];
    const float* Wk   = (const float*)d_in[4];
    const float* bk   = (const float*)d_in[5];
    const float* Wv   = (const float*)d_in[6];
    const float* bv   = (const float*)d_in[7];
    const float* Wcq  = (const float*)d_in[8];
    const float* bcq  = (const float*)d_in[9];
    const float* Wck  = (const float*)d_in[10];
    const float* bck  = (const float*)d_in[11];
    const float* Wcv  = (const float*)d_in[12];
    const float* bcv  = (const float*)d_in[13];
    const float* g_q  = (const float*)d_in[14];
    const float* be_q = (const float*)d_in[15];
    const float* g_qc = (const float*)d_in[16];
    const float* be_qc= (const float*)d_in[17];
    const float* g_k  = (const float*)d_in[18];
    const float* be_k = (const float*)d_in[19];
    const float* g_kc = (const float*)d_in[20];
    const float* be_kc= (const float*)d_in[21];
    const float* g_v  = (const float*)d_in[22];
    const float* be_v = (const float*)d_in[23];
    const float* g_vc = (const float*)d_in[24];
    const float* be_vc= (const float*)d_in[25];
    const float* Wo   = (const float*)d_in[26];
    const float* bo   = (const float*)d_in[27];

    const size_t MD = (size_t)MROWS * D_;     // 8388608
    const size_t MK = (size_t)D_ * D_;        // 1048576

    float* pb   = (float*)d_ws;       // 3*MD floats (proj outputs q|k|v)
    float* cvec = pb + 3 * MD;        // 3*B*D
    u16* U    = (u16*)(cvec + 3 * B_ * D_);
    u16* QsA  = U;                    // 3*MD: proj A-splits; later attn q-splits
    u16* Kh   = U + 3 * MD;           // 3*MD: kh|km|kl
    u16* Vh   = U + 6 * MD;           // MD
    u16* Wqt  = U + 7 * MD;           // 3*MK
    u16* Wkt  = Wqt + 3 * MK;         // 3*MK
    u16* Wvt  = Wkt + 3 * MK;         // MK
    u16* Wot  = Wvt + MK;             // MK
    u16* Ch   = (u16*)d_ws;           // overlay pb (dead after ln_split)
    u16* Vt   = (u16*)d_ws + MD;      // overlay pb after Ch

    float* out_p  = (float*)d_out;
    float* attn_p = (float*)d_out + MD;

    // input conversions
    convA_kernel<3><<<2048, 256, 0, stream>>>(Q, QsA, QsA + MD, QsA + 2 * MD, (int)(MD / 4));
    convW_kernel<3><<<dim3(16, 16), 256, 0, stream>>>(Wq, Wqt, Wqt + MK, Wqt + 2 * MK);
    convW_kernel<3><<<dim3(16, 16), 256, 0, stream>>>(Wk, Wkt, Wkt + MK, Wkt + 2 * MK);
    convW_kernel<1><<<dim3(16, 16), 256, 0, stream>>>(Wv, Wvt, nullptr, nullptr);
    convW_kernel<1><<<dim3(16, 16), 256, 0, stream>>>(Wo, Wot, nullptr, nullptr);

    // c-path
    cproj_ln_kernel<<<dim3(B_, 3), 256, 0, stream>>>(
        c, Wcq, bcq, g_qc, be_qc, Wck, bck, g_kc, be_kc, Wcv, bcv, g_vc, be_vc, cvec);

    // projections
    dim3 ggrid(8, 64);
    gemm_mfma_kernel<6><<<ggrid, 256, 0, stream>>>(QsA, QsA + MD, QsA + 2 * MD,
        Wqt, Wqt + MK, Wqt + 2 * MK, bq, pb);
    gemm_mfma_kernel<6><<<ggrid, 256, 0, stream>>>(QsA, QsA + MD, QsA + 2 * MD,
        Wkt, Wkt + MK, Wkt + 2 * MK, bk, pb + MD);
    gemm_mfma_kernel<1><<<ggrid, 256, 0, stream>>>(QsA, nullptr, nullptr,
        Wvt, nullptr, nullptr, bv, pb + 2 * MD);

    // LN + c-add + head-major bf16 splits (QsA overlay now holds attn q-splits)
    ln_split_kernel<<<dim3(MROWS, 3), 256, 0, stream>>>(
        pb, g_q, be_q, g_k, be_k, g_v, be_v, cvec,
        QsA, QsA + MD, QsA + 2 * MD, Kh, Kh + MD, Kh + 2 * MD, Vh);

    // V transpose
    vtrans_kernel<<<dim3(128, 16), 256, 0, stream>>>(Vh, Vt);

    // attention (writes attn_p and Ch)
    attn_mfma_kernel<<<dim3(4096), 512, 0, stream>>>(
        QsA, QsA + MD, QsA + 2 * MD, Kh, Kh + MD, Kh + 2 * MD, Vt, attn_p, Ch);

    // output projection
    gemm_mfma_kernel<1><<<ggrid, 256, 0, stream>>>(Ch, nullptr, nullptr,
        Wot, nullptr, nullptr, bo, out_p);
}